// Round 1
// 811.543 us; speedup vs baseline: 1.6741x; 1.6741x over previous
//
#include <hip/hip_runtime.h>
#include <math.h>

typedef unsigned short u16;
typedef unsigned int u32;
typedef _Float16 f16;
typedef __attribute__((ext_vector_type(4))) _Float16 half4;
typedef __attribute__((ext_vector_type(8))) _Float16 half8;
typedef __attribute__((ext_vector_type(4))) float floatx4;

// Problem constants
constexpr int NB = 16384;   // batch rows
constexpr int NF = 2048;    // features (K)
constexpr int NI = 4096;    // intermediate (cols of h)
constexpr int NC = 1000;    // classes
constexpr int NBLK_N = NI / 128;          // 32 column blocks in MFMA path
constexpr int NSLOT = NBLK_N * 4;         // 4 entries per block: top-2 x 2 col-halves
constexpr float EPS_MARGIN = 1e-2f;       // candidate margin; fp16 GEMM err std ~3.6e-4,
                                          // worst ~2e-3 over 6.7e7 cells -> 2.5x headroom

// ---------------------------------------------------------------------------
// helpers
// ---------------------------------------------------------------------------
__device__ inline void async16(const void* g, void* l) {
  __builtin_amdgcn_global_load_lds((const __attribute__((address_space(1))) void*)g,
                                   (__attribute__((address_space(3))) void*)l,
                                   16, 0, 0);
}

// ---------------------------------------------------------------------------
// fp32 -> fp16 (RNE via v_cvt_f16_f32 default mode; RTZ would bias the GEMM).
// 4 elems/thread. Thread 0 zeroes the ambiguity counter (ws re-poisoned to
// 0xAA before every launch).
// ---------------------------------------------------------------------------
__global__ __launch_bounds__(256) void to_f16(const float* __restrict__ in,
                                              f16* __restrict__ out, int n4,
                                              int* zero_me) {
  int i = blockIdx.x * 256 + threadIdx.x;
  if (i == 0 && zero_me) { zero_me[0] = 0; }
  if (i >= n4) return;
  float4 v = ((const float4*)in)[i];
  half4 o;
  o.x = (f16)v.x;
  o.y = (f16)v.y;
  o.z = (f16)v.z;
  o.w = (f16)v.w;
  ((half4*)out)[i] = o;
}

// ---------------------------------------------------------------------------
// Single-pass fp16 MFMA GEMM with fused per-row top-2 argmax. 128x128 tile,
// K-step 32, 4 waves. Staging: wave 0/1 stage A-tile row-halves, wave 2/3
// stage B-tile row-halves via global_load_lds (wave-uniform LDS base, linear
// dest). Each wave owns a 64x64 output quadrant; per-(row, col-half) top-2
// written to DISJOINT slots (slot = bx*4 + (wcol>>5) + {0,1}).
//
// Error budget: fp16 input rounding (2^-11 rel) -> h error std ~3.6e-4,
// max ~2e-3 << EPS_MARGIN/2. Unflagged rows are provably-correct argmax;
// flagged rows recomputed exactly by resolve_chain.
// ---------------------------------------------------------------------------
__global__ __launch_bounds__(256) void mfma_f16_argmax(
    const f16* __restrict__ xh, const f16* __restrict__ wh,
    const float* __restrict__ b1, float* __restrict__ pval,
    int* __restrict__ pidx) {
  __shared__ __attribute__((aligned(16))) f16 lds[2][128][32];
  const int t = threadIdx.x;
  const int wv = t >> 6;
  const int l = t & 63;
  const int n0 = blockIdx.x * 128;
  const int m0 = blockIdx.y * 128;
  const int wrow = (wv & 1) * 64;
  const int wcol = (wv >> 1) * 64;

  // staging role: wv 0/1 -> A rows [0,64)/[64,128); wv 2/3 -> B rows.
  const f16* src = (wv < 2) ? (xh + (size_t)(m0 + (wv & 1) * 64) * NF)
                            : (wh + (size_t)(n0 + (wv & 1) * 64) * NF);
  const f16* lsrc = src + (size_t)(l >> 2) * NF + (l & 3) * 8;
  f16* ldsw = &lds[wv >> 1][(wv & 1) * 64][0];

  floatx4 acc[4][4];
#pragma unroll
  for (int i = 0; i < 4; ++i)
#pragma unroll
    for (int j = 0; j < 4; ++j) acc[i][j] = (floatx4){0.f, 0.f, 0.f, 0.f};

  const int fr = l & 15;  // A-row / B-col within 16-tile; also C col
  const int q = l >> 4;   // quad: k-granule for A/B, row-group for C

  for (int kt = 0; kt < NF; kt += 32) {
#pragma unroll
    for (int inst = 0; inst < 4; ++inst) {
      async16(lsrc + kt + inst * 16 * NF, ldsw + inst * 16 * 32);
    }
    __syncthreads();
    half8 ah[4], bh[4];
#pragma unroll
    for (int i = 0; i < 4; ++i) {
      ah[i] = *(const half8*)&lds[0][wrow + i * 16 + fr][q * 8];
      bh[i] = *(const half8*)&lds[1][wcol + i * 16 + fr][q * 8];
    }
#pragma unroll
    for (int mt = 0; mt < 4; ++mt)
#pragma unroll
      for (int nt = 0; nt < 4; ++nt) {
        acc[mt][nt] = __builtin_amdgcn_mfma_f32_16x16x32_f16(ah[mt], bh[nt], acc[mt][nt], 0, 0, 0);
      }
    __syncthreads();
  }

  // Epilogue: bias + per-row top-2 over this wave's 64 cols.
  float bv[4];
#pragma unroll
  for (int nt = 0; nt < 4; ++nt) bv[nt] = b1[n0 + wcol + nt * 16 + fr];

#pragma unroll
  for (int mt = 0; mt < 4; ++mt) {
#pragma unroll
    for (int r = 0; r < 4; ++r) {
      float v1 = -INFINITY, v2 = -INFINITY;
      int i1 = 0x7fffffff, i2 = 0x7fffffff;
#pragma unroll
      for (int nt = 0; nt < 4; ++nt) {
        float v = acc[mt][nt][r] + bv[nt];
        int c = n0 + wcol + nt * 16 + fr;
        if (v > v1 || (v == v1 && c < i1)) {
          v2 = v1; i2 = i1; v1 = v; i1 = c;
        } else if (v > v2 || (v == v2 && c < i2)) {
          v2 = v; i2 = c;
        }
      }
      // reduce top-2 across the 16 lanes sharing this row (low 4 lane bits)
#pragma unroll
      for (int mm = 1; mm < 16; mm <<= 1) {
        float ov1 = __shfl_xor(v1, mm);
        int oi1 = __shfl_xor(i1, mm);
        float ov2 = __shfl_xor(v2, mm);
        int oi2 = __shfl_xor(i2, mm);
        if (ov1 > v1 || (ov1 == v1 && oi1 < i1)) {
          float nv2; int ni2;
          if (v1 > ov2 || (v1 == ov2 && i1 < oi2)) { nv2 = v1; ni2 = i1; }
          else { nv2 = ov2; ni2 = oi2; }
          v1 = ov1; i1 = oi1; v2 = nv2; i2 = ni2;
        } else if (ov1 > v2 || (ov1 == v2 && oi1 < i2)) {
          v2 = ov1; i2 = oi1;
        }
      }
      if (fr == 0) {
        int row = m0 + wrow + mt * 16 + q * 4 + r;
        size_t base = (size_t)row * NSLOT + blockIdx.x * 4 + (wcol >> 5);
        pval[base] = v1; pidx[base] = i1;
        pval[base + 1] = v2; pidx[base + 1] = i2;
      }
    }
  }
}

// ---------------------------------------------------------------------------
// Merge per-slot top-2 -> global approx argmax; flag ambiguous rows.
// ---------------------------------------------------------------------------
__global__ __launch_bounds__(256) void merge_rows(const float* __restrict__ pval,
                                                  const int* __restrict__ pidx,
                                                  int* __restrict__ idxfinal,
                                                  int* __restrict__ amb,
                                                  int* __restrict__ counter) {
  int row = blockIdx.x * 256 + threadIdx.x;
  if (row >= NB) return;
  const float* pv = pval + (size_t)row * NSLOT;
  const int* pi = pidx + (size_t)row * NSLOT;
  float best = -INFINITY;
  int bi = 0x7fffffff;
  for (int e = 0; e < NSLOT; ++e) {
    float v = pv[e];
    int ix = pi[e];
    if (v > best || (v == best && ix < bi)) { best = v; bi = ix; }
  }
  idxfinal[row] = bi;
  float thr = best - EPS_MARGIN;
  int cnt = 0;
  for (int e = 0; e < NSLOT; ++e) cnt += (pv[e] >= thr) ? 1 : 0;
  if (cnt > 1) {
    int p = atomicAdd(counter, 1);
    if (p < NB) amb[p] = row;
  }
}

// ---------------------------------------------------------------------------
// Resolve: for each flagged row, recompute candidate columns with the EXACT
// arithmetic of the known-passing R1 fp32 kernel: a sequential ascending-k
// fmaf chain (acc = fma(x[k], w1[col][k], acc)), then one + b1[col] add.
// One wave per row; lane L handles slots L and L+64. Wave-argmax with
// tie -> smaller column reproduces numpy first-max semantics.
// ---------------------------------------------------------------------------
__global__ __launch_bounds__(256) void resolve_chain(
    const float* __restrict__ x, const float* __restrict__ w1,
    const float* __restrict__ b1, const float* __restrict__ pval,
    const int* __restrict__ pidx, const int* __restrict__ amb,
    const int* __restrict__ counter, int* __restrict__ idxfinal) {
  const int wave = threadIdx.x >> 6;
  const int lane = threadIdx.x & 63;
  int total = counter[0];
  if (total > NB) total = NB;
  for (int e = blockIdx.x * 4 + wave; e < total; e += gridDim.x * 4) {
    const int row = amb[e];
    const float* pv = pval + (size_t)row * NSLOT;
    const int* pi = pidx + (size_t)row * NSLOT;
    // wave-wide max of slot values -> threshold
    float m0 = pv[lane];
    float m1 = pv[lane + 64];
    float mv = fmaxf(m0, m1);
#pragma unroll
    for (int mm = 1; mm < 64; mm <<= 1) mv = fmaxf(mv, __shfl_xor(mv, mm));
    const float thr = mv - EPS_MARGIN;

    float bestv = -INFINITY;
    int besti = 0x7fffffff;
    const float* xr = x + (size_t)row * NF;
#pragma unroll
    for (int half = 0; half < 2; ++half) {
      const float v = half ? m1 : m0;
      if (v >= thr) {
        const int col = pi[lane + half * 64];
        const float* wr = w1 + (size_t)col * NF;
        float acc = 0.0f;
#pragma unroll 8
        for (int k = 0; k < NF; ++k) acc = fmaf(xr[k], wr[k], acc);
        const float val = acc + b1[col];
        if (val > bestv || (val == bestv && col < besti)) { bestv = val; besti = col; }
      }
    }
    // wave argmax, tie -> smaller column
#pragma unroll
    for (int mm = 1; mm < 64; mm <<= 1) {
      float ov = __shfl_xor(bestv, mm);
      int oi = __shfl_xor(besti, mm);
      if (ov > bestv || (ov == bestv && oi < besti)) { bestv = ov; besti = oi; }
    }
    if (lane == 0 && besti != 0x7fffffff) idxfinal[row] = besti;
  }
}

// ---------------------------------------------------------------------------
// w2 transpose + final gather (coalesced path), plus direct-gather fallback
// ---------------------------------------------------------------------------
__global__ __launch_bounds__(256) void transpose_w2(const float* __restrict__ w2,
                                                    float* __restrict__ w2t) {
  __shared__ float tile[32][33];
  const int x = blockIdx.x * 32 + threadIdx.x;  // col in w2 (0..NI)
  const int y0 = blockIdx.y * 32;               // row in w2 (0..NC)
  for (int j = threadIdx.y; j < 32; j += 8) {
    const int y = y0 + j;
    tile[j][threadIdx.x] = (y < NC) ? w2[(size_t)y * NI + x] : 0.0f;
  }
  __syncthreads();
  const int xo = y0 + threadIdx.x;
  const int yo0 = blockIdx.x * 32;
  for (int j = threadIdx.y; j < 32; j += 8) {
    const int yo = yo0 + j;
    if (xo < NC) w2t[(size_t)yo * NC + xo] = tile[threadIdx.x][j];
  }
}

__global__ __launch_bounds__(256) void gather_out(const int* __restrict__ idxfinal,
                                                  const float* __restrict__ w2t,
                                                  const float* __restrict__ b2,
                                                  float* __restrict__ out) {
  const int b = blockIdx.x;
  const int ix = idxfinal[b];
  const float4* src = (const float4*)(w2t + (size_t)ix * NC);
  const float4* bb = (const float4*)b2;
  float4* dst = (float4*)(out + (size_t)b * NC);
  const int t = threadIdx.x;
  if (t < NC / 4) {
    float4 v = src[t];
    float4 w = bb[t];
    float4 o;
    o.x = v.x + w.x; o.y = v.y + w.y; o.z = v.z + w.z; o.w = v.w + w.w;
    dst[t] = o;
  }
}

__global__ __launch_bounds__(256) void gather_out_direct(
    const int* __restrict__ idxfinal, const float* __restrict__ w2,
    const float* __restrict__ b2, float* __restrict__ out) {
  const int b = blockIdx.x;
  const int ix = idxfinal[b];
  for (int c = threadIdx.x; c < NC; c += 256) {
    out[(size_t)b * NC + c] = w2[(size_t)c * NI + ix] + b2[c];
  }
}

// ===========================================================================
// Fallback fp32 path (round-1, known-passing) if workspace is too small.
// ===========================================================================
constexpr int BM = 64, BN = 64, BK = 32, TM = 4, TN = 4;
constexpr int NSPLIT = 8;
constexpr int COLS_PER_SPLIT = NI / NSPLIT;
constexpr int NCHUNK = COLS_PER_SPLIT / BN;
constexpr int LDS_STRIDE = BM + 4;

__global__ __launch_bounds__(256) void argmax_gemm(
    const float* __restrict__ x, const float* __restrict__ w1,
    const float* __restrict__ b1, float* __restrict__ pval,
    int* __restrict__ pidx) {
  __shared__ float xs[BK][LDS_STRIDE];
  __shared__ float ws[BK][LDS_STRIDE];
  const int t = threadIdx.x;
  const int tx = t & 15;
  const int ty = t >> 4;
  const int m0 = blockIdx.x * BM;
  const int split = blockIdx.y;
  const int n0 = split * COLS_PER_SPLIT;
  const int lrow = t >> 3;
  const int lk4 = (t & 7) << 2;
  float rmax[TM];
  int ridx[TM];
#pragma unroll
  for (int i = 0; i < TM; ++i) { rmax[i] = -INFINITY; ridx[i] = 0; }
  for (int chunk = 0; chunk < NCHUNK; ++chunk) {
    const int nb = n0 + chunk * BN;
    float acc[TM][TN];
#pragma unroll
    for (int i = 0; i < TM; ++i)
#pragma unroll
      for (int j = 0; j < TN; ++j) acc[i][j] = 0.0f;
    for (int kt = 0; kt < NF; kt += BK) {
      __syncthreads();
#pragma unroll
      for (int p = 0; p < 2; ++p) {
        const int row = p * 32 + lrow;
        const float4 v = *(const float4*)(x + (size_t)(m0 + row) * NF + kt + lk4);
        xs[lk4 + 0][row] = v.x; xs[lk4 + 1][row] = v.y;
        xs[lk4 + 2][row] = v.z; xs[lk4 + 3][row] = v.w;
        const float4 u = *(const float4*)(w1 + (size_t)(nb + row) * NF + kt + lk4);
        ws[lk4 + 0][row] = u.x; ws[lk4 + 1][row] = u.y;
        ws[lk4 + 2][row] = u.z; ws[lk4 + 3][row] = u.w;
      }
      __syncthreads();
#pragma unroll
      for (int k = 0; k < BK; ++k) {
        const float4 av = *(const float4*)&xs[k][ty * TM];
        const float4 bv = *(const float4*)&ws[k][tx * TN];
        const float a[TM] = {av.x, av.y, av.z, av.w};
        const float b[TN] = {bv.x, bv.y, bv.z, bv.w};
#pragma unroll
        for (int i = 0; i < TM; ++i)
#pragma unroll
          for (int j = 0; j < TN; ++j) acc[i][j] = fmaf(a[i], b[j], acc[i][j]);
      }
    }
#pragma unroll
    for (int j = 0; j < TN; ++j) {
      const int col = nb + tx * TN + j;
      const float bj = b1[col];
#pragma unroll
      for (int i = 0; i < TM; ++i) {
        const float v = acc[i][j] + bj;
        if (v > rmax[i]) { rmax[i] = v; ridx[i] = col; }
      }
    }
  }
#pragma unroll
  for (int m = 1; m < 16; m <<= 1) {
#pragma unroll
    for (int i = 0; i < TM; ++i) {
      const float v2 = __shfl_xor(rmax[i], m);
      const int i2 = __shfl_xor(ridx[i], m);
      if (v2 > rmax[i] || (v2 == rmax[i] && i2 < ridx[i])) { rmax[i] = v2; ridx[i] = i2; }
    }
  }
  if (tx == 0) {
#pragma unroll
    for (int i = 0; i < TM; ++i) {
      const int row = m0 + ty * TM + i;
      pval[(size_t)row * NSPLIT + split] = rmax[i];
      pidx[(size_t)row * NSPLIT + split] = ridx[i];
    }
  }
}

__global__ __launch_bounds__(256) void merge_gather_direct(
    const float* __restrict__ pval, const int* __restrict__ pidx,
    const float* __restrict__ w2, const float* __restrict__ b2,
    float* __restrict__ out) {
  const int b = blockIdx.x;
  __shared__ int sidx;
  if (threadIdx.x == 0) {
    float best = -INFINITY;
    int bi = 0;
    for (int s = 0; s < NSPLIT; ++s) {
      const float v = pval[(size_t)b * NSPLIT + s];
      const int ix = pidx[(size_t)b * NSPLIT + s];
      if (v > best || (v == best && ix < bi)) { best = v; bi = ix; }
    }
    sidx = bi;
  }
  __syncthreads();
  const int ix = sidx;
  for (int c = threadIdx.x; c < NC; c += 256) {
    out[(size_t)b * NC + c] = w2[(size_t)c * NI + ix] + b2[c];
  }
}

// ===========================================================================
extern "C" void kernel_launch(void* const* d_in, const int* in_sizes, int n_in,
                              void* d_out, int out_size, void* d_ws, size_t ws_size,
                              hipStream_t stream) {
  const float* x = (const float*)d_in[0];
  const float* w1 = (const float*)d_in[1];
  const float* b1 = (const float*)d_in[2];
  const float* w2 = (const float*)d_in[3];
  const float* b2 = (const float*)d_in[4];
  float* out = (float*)d_out;

  // workspace layout (bytes)
  const size_t sz_xh = (size_t)NB * NF * 2;          // 33554432*2 = 67108864
  const size_t sz_wh = (size_t)NI * NF * 2;          // 16777216
  const size_t sz_pv = (size_t)NB * NSLOT * 4;       // 8388608
  const size_t sz_idx = (size_t)NB * 4;              // 65536
  const size_t sz_w2t = (size_t)NI * NC * 4;         // 16384000
  const size_t NEED_CORE = sz_xh + sz_wh + 2 * sz_pv + 2 * sz_idx + 16;
  const size_t NEED_FULL = NEED_CORE + sz_w2t;

  if (ws_size >= NEED_CORE) {
    char* p = (char*)d_ws;
    f16* xh = (f16*)p; p += sz_xh;
    f16* wh = (f16*)p; p += sz_wh;
    float* pval = (float*)p; p += sz_pv;
    int* pidx = (int*)p; p += sz_pv;
    int* idxfinal = (int*)p; p += sz_idx;
    int* amb = (int*)p; p += sz_idx;
    int* counter = (int*)p; p += 16;
    const bool have_w2t = ws_size >= NEED_FULL;
    float* w2t = (float*)p;

    to_f16<<<(NB * NF / 4 + 255) / 256, 256, 0, stream>>>(x, xh, NB * NF / 4, counter);
    to_f16<<<(NI * NF / 4 + 255) / 256, 256, 0, stream>>>(w1, wh, NI * NF / 4, nullptr);
    if (have_w2t) {
      dim3 tgrid(NI / 32, (NC + 31) / 32);
      dim3 tblock(32, 8);
      transpose_w2<<<tgrid, tblock, 0, stream>>>(w2, w2t);
    }

    dim3 ggrid(NI / 128, NB / 128);  // n fast-varying for x-tile L2 reuse
    mfma_f16_argmax<<<ggrid, 256, 0, stream>>>(xh, wh, b1, pval, pidx);

    merge_rows<<<NB / 256, 256, 0, stream>>>(pval, pidx, idxfinal, amb, counter);
    resolve_chain<<<256, 256, 0, stream>>>(x, w1, b1, pval, pidx, amb, counter, idxfinal);
    if (have_w2t) {
      gather_out<<<NB, 256, 0, stream>>>(idxfinal, w2t, b2, out);
    } else {
      gather_out_direct<<<NB, 256, 0, stream>>>(idxfinal, w2, b2, out);
    }
  } else {
    // fp32 fallback (round-1 path)
    float* pval = (float*)d_ws;
    int* pidx = (int*)((float*)d_ws + (size_t)NB * NSPLIT);
    dim3 ggrid(NB / BM, NSPLIT);
    argmax_gemm<<<ggrid, 256, 0, stream>>>(x, w1, b1, pval, pidx);
    merge_gather_direct<<<NB, 256, 0, stream>>>(pval, pidx, w2, b2, out);
  }
}